// Round 4
// baseline (384.573 us; speedup 1.0000x reference)
//
#include <hip/hip_runtime.h>

#define BATCH 4096
#define F 39
#define G 13                         // field-group size: 3 groups of 13
#define E 16
#define NTILE 6                      // (0,0)(1,1)(2,2)(0,1)(0,2)(1,2)
#define CHUNK_F4 (G * E / 4)         // 52 float4 per (row, group) chunk (832 B)
#define TILE_F4  (G * CHUNK_F4)      // 676 float4 per tile side
#define BLOCK 384
#define NWAVES (BLOCK / 64)          // 6

// unranked upper-triangle pairs (ii<jj) over 13
__device__ __constant__ unsigned char PI[78] = {
    0,0,0,0,0,0,0,0,0,0,0,0,
    1,1,1,1,1,1,1,1,1,1,1,
    2,2,2,2,2,2,2,2,2,2,
    3,3,3,3,3,3,3,3,3,
    4,4,4,4,4,4,4,4,
    5,5,5,5,5,5,5,
    6,6,6,6,6,6,
    7,7,7,7,7,
    8,8,8,8,
    9,9,9,
    10,10,
    11};
__device__ __constant__ unsigned char PJ[78] = {
    1,2,3,4,5,6,7,8,9,10,11,12,
    2,3,4,5,6,7,8,9,10,11,12,
    3,4,5,6,7,8,9,10,11,12,
    4,5,6,7,8,9,10,11,12,
    5,6,7,8,9,10,11,12,
    6,7,8,9,10,11,12,
    7,8,9,10,11,12,
    8,9,10,11,12,
    9,10,11,12,
    10,11,12,
    11,12,
    12};

__global__ __launch_bounds__(BLOCK) void ffm_tile(
    const int*   __restrict__ idx,    // [B, F]
    const float* __restrict__ vals,   // [B, F]
    const float* __restrict__ emb,    // [100000, F, E]
    const float* __restrict__ w1,     // [100000, 1]
    float*       __restrict__ ws)     // [NTILE, BATCH] partial sums
{
    const int bx   = blockIdx.x;
    const int brow = bx / NTILE;             // magic-mul
    const int t    = bx - brow * NTILE;
    const int ta_[NTILE] = {0, 1, 2, 0, 0, 1};
    const int tb_[NTILE] = {0, 1, 2, 1, 2, 2};
    const int ga = ta_[t], gb = tb_[t];
    const bool diag = (ga == gb);
    const int tid = threadIdx.x;

    // sA[ii][jj][e] : row ga*G+ii, slice j = gb*G+jj   (21.6 KB total LDS)
    // sB[jj][ii][e] : row gb*G+jj, slice i = ga*G+ii
    __shared__ __align__(16) float sA[G * G * E];
    __shared__ __align__(16) float sB[G * G * E];
    __shared__ int   iA[G], iB[G];
    __shared__ float vA[G], vB[G];
    __shared__ float s_red[NWAVES];

    if (tid < G) {
        iA[tid] = idx[brow * F + ga * G + tid];
        vA[tid] = vals[brow * F + ga * G + tid];
    } else if (tid >= 64 && tid < 64 + G) {
        int k = tid - 64;
        iB[k] = idx[brow * F + gb * G + k];
        vB[k] = vals[brow * F + gb * G + k];
    }
    __syncthreads();

    // ---- Stage: contiguous 832 B chunks, fp32, coalesced float4 ----
    const float4* emb4 = (const float4*)emb;
    float4* sA4 = (float4*)sA;
    float4* sB4 = (float4*)sB;
    const int total = diag ? TILE_F4 : 2 * TILE_F4;
    for (int u = tid; u < total; u += BLOCK) {
        int side = u >= TILE_F4;             // 0 = A-side, 1 = B-side
        int v    = u - side * TILE_F4;
        int r    = v / CHUNK_F4;             // which row within group
        int off  = v - r * CHUNK_F4;
        int grow    = side ? iB[r] : iA[r];
        int gslice0 = side ? ga * G : gb * G;
        float4 x = emb4[(grow * F + gslice0) * (E / 4) + off];
        if (side) sB4[v] = x; else sA4[v] = x;
    }

    // First-order term (each field handled once, in its diagonal tile)
    float acc = 0.0f;
    if (diag && tid < G) acc = vA[tid] * w1[iA[tid]];
    __syncthreads();

    // ---- Pairs from LDS: 2 lanes/pair, 32 B per operand per lane ----
    if (diag) {
        if (tid < 78 * 2) {
            int p = tid >> 1, h = tid & 1;
            int ii = PI[p], jj = PJ[p];
            const float* a = &sA[(ii * G + jj) * E + h * 8];
            const float* b = &sA[(jj * G + ii) * E + h * 8];
            float dot = 0.0f;
            #pragma unroll
            for (int e = 0; e < 8; ++e) dot += a[e] * b[e];
            acc += dot * (vA[ii] * vA[jj]);
        }
    } else {
        if (tid < 169 * 2) {
            int p = tid >> 1, h = tid & 1;
            int ii = p / G, jj = p - ii * G;
            const float* a = &sA[(ii * G + jj) * E + h * 8];
            const float* b = &sB[(jj * G + ii) * E + h * 8];
            float dot = 0.0f;
            #pragma unroll
            for (int e = 0; e < 8; ++e) dot += a[e] * b[e];
            acc += dot * (vA[ii] * vB[jj]);
        }
    }

    // ---- Reduce: 64-lane shuffle, cross-wave via LDS ----
    #pragma unroll
    for (int off = 32; off > 0; off >>= 1)
        acc += __shfl_down(acc, off, 64);
    const int wave = tid >> 6;
    const int lane = tid & 63;
    if (lane == 0) s_red[wave] = acc;
    __syncthreads();

    if (tid == 0) {
        float s = 0.0f;
        #pragma unroll
        for (int w = 0; w < NWAVES; ++w) s += s_red[w];
        ws[t * BATCH + brow] = s;
    }
}

__global__ void ffm_finish(const float* __restrict__ ws,
                           const float* __restrict__ bias,
                           float*       __restrict__ out) {
    int b = blockIdx.x * blockDim.x + threadIdx.x;
    if (b < BATCH) {
        float s = bias[0];
        #pragma unroll
        for (int t = 0; t < NTILE; ++t) s += ws[t * BATCH + b];
        out[b] = s;
    }
}

extern "C" void kernel_launch(void* const* d_in, const int* in_sizes, int n_in,
                              void* d_out, int out_size, void* d_ws, size_t ws_size,
                              hipStream_t stream) {
    const int*   idx  = (const int*)d_in[0];
    const float* vals = (const float*)d_in[1];
    const float* emb  = (const float*)d_in[2];
    const float* w1   = (const float*)d_in[3];
    const float* bias = (const float*)d_in[4];
    float* out = (float*)d_out;
    float* ws  = (float*)d_ws;     // NTILE * BATCH floats = 96 KB

    ffm_tile<<<BATCH * NTILE, BLOCK, 0, stream>>>(idx, vals, emb, w1, ws);
    ffm_finish<<<(BATCH + 255) / 256, 256, 0, stream>>>(ws, bias, out);
}